// Round 9
// baseline (221.440 us; speedup 1.0000x reference)
//
#include <hip/hip_runtime.h>

#define T_PRIOR 168
#define N_FEAT 11
#define DEC_FEAT 7
#define HID 64
#define T_DEC 48
#define BATCH 8192
#define XROW 132                 // uints per staged row (8 slots x 16 words + 4 spare)
#define ROWB (XROW*4)            // 528 B
#define BUFB (16*ROWB)           // 8448 B per chunk buffer

typedef __attribute__((ext_vector_type(8))) short short8;
typedef __attribute__((ext_vector_type(4))) float f32x4;
typedef __attribute__((ext_vector_type(2))) float f32x2;
typedef __attribute__((ext_vector_type(4))) int i32x4;

#define MFMA __builtin_amdgcn_mfma_f32_16x16x32_bf16

static __device__ __forceinline__ unsigned fbits(float f){union{float f;unsigned u;}v;v.f=f;return v.u;}
static __device__ __forceinline__ float bitsf(unsigned u){union{unsigned u;float f;}v;v.u=u;return v.f;}
static __device__ __forceinline__ unsigned short bf16rne(float f){
    unsigned x=fbits(f);
    return (unsigned short)((x+0x7fffu+((x>>16)&1u))>>16);
}
static __device__ __forceinline__ float sigm(float x){ return __builtin_amdgcn_rcpf(1.0f + __expf(-x)); }
static __device__ __forceinline__ float tanhf_(float x){ return fmaf(2.0f, __builtin_amdgcn_rcpf(1.0f + __expf(-2.0f*x)), -1.0f); }
static __device__ __forceinline__ short8 s8(i32x4 v){union{i32x4 i;short8 s;}q;q.i=v;return q.s;}
// packed word: high16 = bf16(hi-trunc), low16 = bf16(lo-residual-trunc)
// as a bf16 k-PAIR (k-even = low16 = lo, k-odd = high16 = hi); B dupes weight on both slots
static __device__ __forceinline__ unsigned packw(float x){
    unsigned hi = fbits(x) & 0xffff0000u;
    return hi | (fbits(x - bitsf(hi)) >> 16);
}

__global__ __launch_bounds__(512) __attribute__((amdgpu_waves_per_eu(4,4)))
void gru_mfma(const float* __restrict__ prior, const float* __restrict__ teacher,
              const float* __restrict__ eWih, const float* __restrict__ eWhh,
              const float* __restrict__ eBih, const float* __restrict__ eBhh,
              const float* __restrict__ dWih, const float* __restrict__ dWhh,
              const float* __restrict__ dBih, const float* __restrict__ dBhh,
              const float* __restrict__ fcW, const float* __restrict__ fcB,
              float* __restrict__ out)
{
    __shared__ __align__(16) unsigned sH[16*64];          // [row][kappa2], 256B/row, XOR-swizzled, hi|lo packed
    __shared__ __align__(16) float sXch[2][4][4][128];    // [s][u][gate R,Z,H,I][lane*2] partial exchange
    __shared__ __align__(16) unsigned sX[2*16*XROW];      // pre-packed inputs, chunk dbuf
    __shared__ __align__(16) float sPartial[16][4];       // [row][u]

    const int tid  = (int)threadIdx.x;
    const int lane = tid & 63;
    const int w    = tid >> 6;                             // 0..7
    const int u    = w & 3;                                // unit tile
    const int sW   = __builtin_amdgcn_readfirstlane(w >> 2);   // K-half
    const int c    = lane & 15;
    const int g    = lane >> 4;
    const int row0 = (int)blockIdx.x * 16;

    // ---- hoisted addresses ----
    const unsigned cs4 = ((unsigned)(c & 7)) << 4;
    const unsigned rdH0 = (unsigned)(c*256) + (((unsigned)(sW*128 +      g*16)) ^ cs4);
    const unsigned rdH1 = (unsigned)(c*256) + (((unsigned)(sW*128 + 64 + g*16)) ^ cs4);
    unsigned pubOff[2];
#pragma unroll
    for (int q = 0; q < 2; ++q) {
        int rr = g*4 + sW*2 + q;
        pubOff[q] = (unsigned)(rr*256) + ((unsigned)((c*4 + u)*4) ^ (((unsigned)(rr & 7)) << 4));
    }
    const unsigned rdX = (unsigned)(c*ROWB) + (unsigned)(g*16);    // + slot*64
    float* xchW = &sXch[sW][u][0][0];
    const float* xchR = &sXch[sW^1][u][0][0];

    // ---- staging setup (threads 0..255 only) ----
    const bool stager = (tid < 256);
    const int srow = (tid & 255) >> 4, sli = tid & 15;
    char* sXwr = (char*)sX + srow*ROWB;
    int offE[6], offD[4];
#pragma unroll
    for (int n = 0; n < 6; ++n) { int k = sli + 16*n; offE[n] = ((k/11)*16 + (k%11))*4; }
#pragma unroll
    for (int n = 0; n < 4; ++n) { int k = sli + 16*n; offD[n] = ((k/7)*16 + (k%7))*4; }
    const float* gP = prior   + (size_t)(row0 + srow)*(T_PRIOR*N_FEAT) + sli;
    const float* gT = teacher + (size_t)(row0 + srow)*(T_DEC*DEC_FEAT) + sli;

    // ---- per-wave weights ----
    short8 BHH[3][2];        // [gate][kt], k2-pair-duplicated, kappa-permuted
    short8 BIx[2];           // sW==0: [I]; sW==1: [R, Z]
    f32x4 cR, cZ, cH, bI4;   // C-in (biases on s0, zeros on s1)

    auto loadPhase = [&](const float* Wih, const float* Whh,
                         const float* bih, const float* bhh, int kv) {
        const int rwb = u*16 + c;
#pragma unroll
        for (int gate = 0; gate < 3; ++gate) {
            const int rw = gate*64 + rwb;
#pragma unroll
            for (int kt = 0; kt < 2; ++kt) {
                union { short8 v; unsigned short s_[8]; } fh;
#pragma unroll
                for (int j = 0; j < 8; ++j) {
                    int k2 = sW*32 + kt*16 + g*4 + (j >> 1);     // k-pair index
                    int unit = ((k2 & 3) << 4) | (k2 >> 2);      // kappa permutation
                    fh.s_[j] = bf16rne(Whh[rw*64 + unit]);
                }
                BHH[gate][kt] = fh.v;
            }
        }
        auto mkBI = [&](int gate) -> short8 {
            const int rw = gate*64 + rwb;
            union { short8 v; unsigned short s_[8]; } fi;
#pragma unroll
            for (int j = 0; j < 8; ++j) {
                int f = g*4 + (j >> 1);                          // feature index
                fi.s_[j] = (f < kv) ? bf16rne(Wih[rw*kv + f]) : (unsigned short)0;
            }
            return fi.v;
        };
        const int un = u*16 + c;
        if (sW == 0) {
            BIx[0] = mkBI(2);                                    // i_n
            float vR = bih[un] + bhh[un];
            float vZ = bih[64+un] + bhh[64+un];
            float vH = bhh[128+un];
            float vI = bih[128+un];
            cR = (f32x4){vR,vR,vR,vR};
            cZ = (f32x4){vZ,vZ,vZ,vZ};
            cH = (f32x4){vH,vH,vH,vH};
            bI4 = (f32x4){vI,vI,vI,vI};
        } else {
            BIx[0] = mkBI(0); BIx[1] = mkBI(1);                  // r, z
            cR = (f32x4){0,0,0,0}; cZ = cR; cH = cR; bI4 = cR;
        }
    };

    f32x4 accR, accZ, accH, accI;
    float h0 = 0.0f, h1 = 0.0f;

    // phase1: read h A-frags + x, partial MFMAs, write partner's rows to xch
    auto phase1 = [&](short8 xf) {
        short8 a0 = *(const short8*)((const char*)sH + rdH0);
        short8 a1 = *(const short8*)((const char*)sH + rdH1);
        accR = MFMA(a0, BHH[0][0], cR, 0,0,0);
        accZ = MFMA(a0, BHH[1][0], cZ, 0,0,0);
        accH = MFMA(a0, BHH[2][0], cH, 0,0,0);
        accR = MFMA(a1, BHH[0][1], accR, 0,0,0);
        accZ = MFMA(a1, BHH[1][1], accZ, 0,0,0);
        accH = MFMA(a1, BHH[2][1], accH, 0,0,0);
        if (sW == 0) {
            accI = MFMA(xf, BIx[0], bI4, 0,0,0);
            *(f32x2*)&xchW[0*128 + lane*2] = (f32x2){accR[2], accR[3]};
            *(f32x2*)&xchW[1*128 + lane*2] = (f32x2){accZ[2], accZ[3]};
            *(f32x2*)&xchW[2*128 + lane*2] = (f32x2){accH[2], accH[3]};
            *(f32x2*)&xchW[3*128 + lane*2] = (f32x2){accI[2], accI[3]};
        } else {
            accR = MFMA(xf, BIx[0], accR, 0,0,0);
            accZ = MFMA(xf, BIx[1], accZ, 0,0,0);
            *(f32x2*)&xchW[0*128 + lane*2] = (f32x2){accR[0], accR[1]};
            *(f32x2*)&xchW[1*128 + lane*2] = (f32x2){accZ[0], accZ[1]};
            *(f32x2*)&xchW[2*128 + lane*2] = (f32x2){accH[0], accH[1]};
        }
    };

    // phase2: combine partner partials, gates (2 rows), publish packed h
    auto phase2 = [&]() {
        f32x2 pR = *(const f32x2*)&xchR[0*128 + lane*2];
        f32x2 pZ = *(const f32x2*)&xchR[1*128 + lane*2];
        f32x2 pH = *(const f32x2*)&xchR[2*128 + lane*2];
        float Rt0, Rt1, Zt0, Zt1, Ht0, Ht1, It0, It1;
        if (sW == 0) {
            Rt0 = accR[0] + pR[0]; Rt1 = accR[1] + pR[1];
            Zt0 = accZ[0] + pZ[0]; Zt1 = accZ[1] + pZ[1];
            Ht0 = accH[0] + pH[0]; Ht1 = accH[1] + pH[1];
            It0 = accI[0];         It1 = accI[1];
        } else {
            f32x2 pI = *(const f32x2*)&xchR[3*128 + lane*2];
            Rt0 = accR[2] + pR[0]; Rt1 = accR[3] + pR[1];
            Zt0 = accZ[2] + pZ[0]; Zt1 = accZ[3] + pZ[1];
            Ht0 = accH[2] + pH[0]; Ht1 = accH[3] + pH[1];
            It0 = pI[0];           It1 = pI[1];
        }
        float rr0 = sigm(Rt0), zz0 = sigm(Zt0);
        float nn0 = tanhf_(fmaf(rr0, Ht0, It0));
        h0 = nn0 + zz0*(h0 - nn0);
        float rr1 = sigm(Rt1), zz1 = sigm(Zt1);
        float nn1 = tanhf_(fmaf(rr1, Ht1, It1));
        h1 = nn1 + zz1*(h1 - nn1);
        *(unsigned*)((char*)sH + pubOff[0]) = packw(h0);
        *(unsigned*)((char*)sH + pubOff[1]) = packw(h1);
    };

    // ---------------- prologue ----------------
#pragma unroll
    for (int it = 0; it < 2; ++it) sH[tid + 512*it] = 0u;       // h(0) = 0
    // zero encoder pad words 11..15, both buffers (1280 entries)
#pragma unroll
    for (int it = 0; it < 3; ++it) {
        int e = tid + 512*it;
        if (e < 1280) {
            int b = e / 640, r = (e - b*640) / 40, rem = e % 40;
            sX[b*(16*XROW) + r*XROW + (rem/5)*16 + 11 + rem%5] = 0u;
        }
    }
    loadPhase(eWih, eWhh, eBih, eBhh, N_FEAT);
    if (stager) {   // stage encoder chunk 0
        float sv[6];
#pragma unroll
        for (int n = 0; n < 5; ++n) sv[n] = gP[16*n];
        sv[5] = (sli < 8) ? gP[80] : 0.0f;
#pragma unroll
        for (int n = 0; n < 5; ++n) *(unsigned*)(sXwr + offE[n]) = packw(sv[n]);
        if (sli < 8) *(unsigned*)(sXwr + offE[5]) = packw(sv[5]);
    }

    // ---------------- encoder: 21 chunks x 8 steps ----------------
    for (int ch = 0; ch < 21; ++ch) {
        const unsigned bo  = (unsigned)((ch & 1) * BUFB);
        const unsigned wbo = (unsigned)(((ch + 1) & 1) * BUFB);
        const bool st = (ch < 20);
        float sv[6];
#pragma unroll
        for (int s = 0; s < 8; ++s) {
            __syncthreads();                       // barrier1: sH(t), sX chunk, xch free
            if (s == 0 && st && stager) {
                const float* sp = gP + 88*(ch+1);
#pragma unroll
                for (int n = 0; n < 5; ++n) sv[n] = sp[16*n];
                sv[5] = (sli < 8) ? sp[80] : 0.0f;
            }
            short8 xf = *(const short8*)((const char*)sX + (bo + rdX + (unsigned)(s*64)));
            phase1(xf);
            __syncthreads();                       // barrier2: xch ready, sH reads done
            phase2();
            if (s == 0 && st && stager) {
#pragma unroll
                for (int n = 0; n < 5; ++n) *(unsigned*)(sXwr + wbo + offE[n]) = packw(sv[n]);
                if (sli < 8) *(unsigned*)(sXwr + wbo + offE[5]) = packw(sv[5]);
            }
        }
    }

    // ---------------- decoder setup ----------------
    loadPhase(dWih, dWhh, dBih, dBhh, DEC_FEAT);
    const float fwc = fcW[u*16 + c];
    const float fb  = fcB[0];
    // zero decoder pad words 7..10, both buffers (1024 entries); safe: all waves past
    // barrier2(167) => every encoder sX read retired
#pragma unroll
    for (int it = 0; it < 2; ++it) {
        int e = tid + 512*it;
        int b = e / 512, r = (e - b*512) / 32, rem = e % 32;
        sX[b*(16*XROW) + r*XROW + (rem/4)*16 + 7 + (rem & 3)] = 0u;
    }
    if (stager) {   // stage decoder chunk 0 into buffer 0
        float sv[4];
#pragma unroll
        for (int n = 0; n < 3; ++n) sv[n] = gT[16*n];
        sv[3] = (sli < 8) ? gT[48] : 0.0f;
#pragma unroll
        for (int n = 0; n < 3; ++n) *(unsigned*)(sXwr + offD[n]) = packw(sv[n]);
        if (sli < 8) *(unsigned*)(sXwr + offD[3]) = packw(sv[3]);
    }

    // ---------------- decoder: 6 chunks x 8 steps ----------------
    for (int ch = 0; ch < 6; ++ch) {
        const unsigned bo  = (unsigned)((ch & 1) * BUFB);
        const unsigned wbo = (unsigned)(((ch + 1) & 1) * BUFB);
        const bool st = (ch < 5);
        float sv[4];
#pragma unroll
        for (int s = 0; s < 8; ++s) {
            const int i = ch*8 + s;
            __syncthreads();                       // barrier1
            if (s == 0 && st && stager) {
                const float* sp = gT + 56*(ch+1);
#pragma unroll
                for (int n = 0; n < 3; ++n) sv[n] = sp[16*n];
                sv[3] = (sli < 8) ? sp[48] : 0.0f;
            }
            const bool hasPred = (i > 0);
            i32x4 xi = *(const i32x4*)((const char*)sX + (bo + rdX + (unsigned)(s*64)));
            if (hasPred) {                          // pred_{i-1}
                f32x4 pp = *(const f32x4*)&sPartial[c][0];
                float pred = pp[0] + pp[1] + pp[2] + pp[3] + fb;
                if (g == 1) xi[0] = (int)packw(pred);   // feature 4 k-pair
                if (w == 0 && g == 0)
                    out[(size_t)(row0 + c)*T_DEC + (i - 1)] = pred;
            }
            phase1(s8(xi));
            __syncthreads();                       // barrier2
            phase2();
            // fc partials: reduce over c (units) within each g-group
            {
                float v0 = h0 * fwc, v1 = h1 * fwc;
                v0 += __shfl_xor(v0, 1, 64); v1 += __shfl_xor(v1, 1, 64);
                v0 += __shfl_xor(v0, 2, 64); v1 += __shfl_xor(v1, 2, 64);
                v0 += __shfl_xor(v0, 4, 64); v1 += __shfl_xor(v1, 4, 64);
                v0 += __shfl_xor(v0, 8, 64); v1 += __shfl_xor(v1, 8, 64);
                if (c == 0) {
                    sPartial[g*4 + sW*2 + 0][u] = v0;
                    sPartial[g*4 + sW*2 + 1][u] = v1;
                }
            }
            if (s == 0 && st && stager) {
#pragma unroll
                for (int n = 0; n < 3; ++n) *(unsigned*)(sXwr + wbo + offD[n]) = packw(sv[n]);
                if (sli < 8) *(unsigned*)(sXwr + wbo + offD[3]) = packw(sv[3]);
            }
        }
    }
    __syncthreads();
    if (w == 0 && g == 0) {   // final pred (i = 47)
        f32x4 pp = *(const f32x4*)&sPartial[c][0];
        float pred = pp[0] + pp[1] + pp[2] + pp[3] + fb;
        out[(size_t)(row0 + c)*T_DEC + (T_DEC - 1)] = pred;
    }
}

extern "C" void kernel_launch(void* const* d_in, const int* in_sizes, int n_in,
                              void* d_out, int out_size, void* d_ws, size_t ws_size,
                              hipStream_t stream)
{
    const float* prior   = (const float*)d_in[0];
    const float* teacher = (const float*)d_in[1];
    const float* eWih    = (const float*)d_in[2];
    const float* eWhh    = (const float*)d_in[3];
    const float* eBih    = (const float*)d_in[4];
    const float* eBhh    = (const float*)d_in[5];
    const float* dWih    = (const float*)d_in[6];
    const float* dWhh    = (const float*)d_in[7];
    const float* dBih    = (const float*)d_in[8];
    const float* dBhh    = (const float*)d_in[9];
    const float* fcW     = (const float*)d_in[10];
    const float* fcB     = (const float*)d_in[11];
    float* out = (float*)d_out;

    dim3 grid(BATCH / 16);    // 512 blocks x 8 waves = 4096 waves (4/SIMD)
    dim3 block(512);
    hipLaunchKernelGGL(gru_mfma, grid, block, 0, stream,
                       prior, teacher, eWih, eWhh, eBih, eBhh,
                       dWih, dWhh, dBih, dBhh, fcW, fcB, out);
}

// Round 10
// 184.733 us; speedup vs baseline: 1.1987x; 1.1987x over previous
//
#include <hip/hip_runtime.h>

#define T_PRIOR 168
#define N_FEAT 11
#define DEC_FEAT 7
#define HID 64
#define T_DEC 48
#define BATCH 8192
#define XROW 220                 // uints per staged row; padded so LDS/block = 36864 B -> exactly 4 blocks/CU
#define ROWB (XROW*4)            // 880 B
#define BUFB (16*ROWB)           // per chunk buffer

typedef __attribute__((ext_vector_type(8))) short short8;
typedef __attribute__((ext_vector_type(4))) float f32x4;
typedef __attribute__((ext_vector_type(4))) int i32x4;
typedef __attribute__((ext_vector_type(4))) unsigned u32x4;

#define MFMA __builtin_amdgcn_mfma_f32_16x16x32_bf16

static __device__ __forceinline__ unsigned fbits(float f){union{float f;unsigned u;}v;v.f=f;return v.u;}
static __device__ __forceinline__ float bitsf(unsigned u){union{unsigned u;float f;}v;v.u=u;return v.f;}
static __device__ __forceinline__ unsigned short bf16rne(float f){
    unsigned x=fbits(f);
    return (unsigned short)((x+0x7fffu+((x>>16)&1u))>>16);
}
// v_rcp_f32-based gates (avoid IEEE div expansion)
static __device__ __forceinline__ float sigm(float x){ return __builtin_amdgcn_rcpf(1.0f + __expf(-x)); }
static __device__ __forceinline__ float tanhf_(float x){ return fmaf(2.0f, __builtin_amdgcn_rcpf(1.0f + __expf(-2.0f*x)), -1.0f); }
static __device__ __forceinline__ short8 s8(i32x4 v){union{i32x4 i;short8 s;}q;q.i=v;return q.s;}
// packed word: bf16-hi (truncated) in high 16 bits, bf16-lo (truncated residual) in low 16
static __device__ __forceinline__ unsigned packw(float x){
    unsigned hi = fbits(x) & 0xffff0000u;
    return hi | (fbits(x - bitsf(hi)) >> 16);
}

__global__ __launch_bounds__(256) __attribute__((amdgpu_waves_per_eu(2,4)))
void gru_mfma(const float* __restrict__ prior, const float* __restrict__ teacher,
              const float* __restrict__ eWih, const float* __restrict__ eWhh,
              const float* __restrict__ eBih, const float* __restrict__ eBhh,
              const float* __restrict__ dWih, const float* __restrict__ dWhh,
              const float* __restrict__ dBih, const float* __restrict__ dBhh,
              const float* __restrict__ fcW, const float* __restrict__ fcB,
              float* __restrict__ out)
{
    __shared__ __align__(16) unsigned short sHhi[2][1024];   // [parity][16 rows x 64 kappa], swizzled
    __shared__ __align__(16) unsigned short sHlo[2][1024];
    __shared__ __align__(16) unsigned sX[2*16*XROW];         // pre-packed (hi|lo) inputs, chunk dbuf
    __shared__ __align__(16) float sPartial[2][16][4];       // [parity][row][u]

    const int tid  = (int)threadIdx.x;
    const int lane = tid & 63;
    const int u    = tid >> 6;       // wave id = unit tile (full K per wave)
    const int c    = lane & 15;      // batch row / B col
    const int g    = lane >> 4;      // k-group
    const int row0 = (int)blockIdx.x * 16;

    // ---- sH fragment offsets (kappa layout, XOR-swizzled; proven in R4-R8) ----
    const unsigned cs = ((unsigned)(c & 7)) << 4;
    const unsigned rbA0 = (unsigned)(c*128) + (((unsigned)(g*16)) ^ cs);       // K 0..31
    const unsigned rbA1 = (unsigned)(c*128) + (((unsigned)(64 + g*16)) ^ cs);  // K 32..63
    unsigned pubOff[4];
#pragma unroll
    for (int q = 0; q < 4; ++q) {
        int r = g*4 + q;
        pubOff[q] = (unsigned)(r*128) + (((unsigned)(c*8 + u*2)) ^ (((unsigned)(r&7))<<4));
    }

    // ---- per-lane x-fragment tables (K-packing: k<kv -> hi f_k; 12<=k<12+kv -> lo f_{k-12}) ----
    const unsigned HI5 = 0x07060302u, LO5 = 0x05040100u;   // v_perm sels: hi-pair / lo-pair
    unsigned eA, eB, dA, dB, s01E, s23E, s01D, s23D;
    bool pA_, pB_;
    if (g == 0)      { eA=0;  eB=16; s01E=HI5; s23E=HI5; dA=0;  dB=16; s01D=HI5; s23D=HI5; pA_=false; pB_=true;  }
    else if (g == 1) { eA=32; eB=0;  s01E=HI5; s23E=LO5; dA=48; dB=0;  s01D=HI5; s23D=LO5; pA_=false; pB_=false; }
    else if (g == 2) { eA=16; eB=32; s01E=LO5; s23E=LO5; dA=16; dB=48; s01D=LO5; s23D=LO5; pA_=true;  pB_=false; }
    else             { eA=48; eB=48; s01E=HI5; s23E=HI5; dA=48; dB=48; s01D=HI5; s23D=HI5; pA_=false; pB_=false; }
    // offset 48 = slot words 12..15 = permanent zero pad
    const unsigned rdEA = (unsigned)(c*ROWB) + eA;
    const unsigned rdEB = (unsigned)(c*ROWB) + eB;
    const unsigned rdDA = (unsigned)(c*ROWB) + dA;
    const unsigned rdDB = (unsigned)(c*ROWB) + dB;
    char* sXB = (char*)sX;

    // ---- staging setup (all 256 threads) ----
    const int srow = tid >> 4, sli = tid & 15;
    char* sXwr = sXB + srow*ROWB;
    int offE[6], offD[4];
#pragma unroll
    for (int n = 0; n < 6; ++n) { int k = sli + 16*n; offE[n] = ((k/11)*16 + (k%11))*4; }
#pragma unroll
    for (int n = 0; n < 4; ++n) { int k = sli + 16*n; offD[n] = ((k/7)*16 + (k%7))*4; }
    const float* gP = prior   + (size_t)(row0 + srow)*(T_PRIOR*N_FEAT) + sli;
    const float* gT = teacher + (size_t)(row0 + srow)*(T_DEC*DEC_FEAT) + sli;

    // ---- per-wave weights (full K) ----
    short8 BHH[3][2], BIH[3];
    f32x4 bR4, bZ4, bH4, bI4;
    auto loadPhase = [&](const float* Wih, const float* Whh,
                         const float* bih, const float* bhh, int kvalid) {
        const int rwb = u*16 + c;
#pragma unroll
        for (int gate = 0; gate < 3; ++gate) {
            const int rw = gate*64 + rwb;
#pragma unroll
            for (int kt = 0; kt < 2; ++kt) {
                union { short8 v; unsigned short s[8]; } fh;
#pragma unroll
                for (int j = 0; j < 8; ++j) {
                    int kap = kt*32 + g*8 + j;
                    int unit = ((kap & 3) << 4) | (kap >> 2);   // kappa permutation
                    fh.s[j] = bf16rne(Whh[rw*64 + unit]);
                }
                BHH[gate][kt] = fh.v;
            }
            union { short8 v; unsigned short s[8]; } fi;
#pragma unroll
            for (int j = 0; j < 8; ++j) {
                int k = g*8 + j;
                float wv = 0.0f;
                if (k < kvalid) wv = Wih[rw*kvalid + k];
                else if (k >= 12 && k < 12 + kvalid) wv = Wih[rw*kvalid + (k-12)];
                fi.s[j] = bf16rne(wv);
            }
            BIH[gate] = fi.v;
        }
        const int un = u*16 + c;
        float vR = bih[un] + bhh[un];
        float vZ = bih[64+un] + bhh[64+un];
        float vI = bih[128+un];
        float vH = bhh[128+un];
        bR4 = (f32x4){vR,vR,vR,vR};
        bZ4 = (f32x4){vZ,vZ,vZ,vZ};
        bH4 = (f32x4){vH,vH,vH,vH};
        bI4 = (f32x4){vI,vI,vI,vI};
    };

    float h[4] = {0.0f, 0.0f, 0.0f, 0.0f};

    // one GRU step: read h(p) frags, 15 MFMA, gates, publish h into p^1
    auto gru_step = [&](int p, short8 xf) {
        const char* hb = (const char*)&sHhi[p][0];
        const char* lb = (const char*)&sHlo[p][0];
        short8 aH0 = *(const short8*)(hb + rbA0);
        short8 aH1 = *(const short8*)(hb + rbA1);
        short8 aL0 = *(const short8*)(lb + rbA0);
        short8 aL1 = *(const short8*)(lb + rbA1);

        f32x4 R = MFMA(aH0, BHH[0][0], bR4, 0,0,0);
        R = MFMA(aL0, BHH[0][0], R, 0,0,0);
        R = MFMA(aH1, BHH[0][1], R, 0,0,0);
        R = MFMA(aL1, BHH[0][1], R, 0,0,0);
        R = MFMA(xf,  BIH[0],    R, 0,0,0);
        f32x4 Z = MFMA(aH0, BHH[1][0], bZ4, 0,0,0);
        Z = MFMA(aL0, BHH[1][0], Z, 0,0,0);
        Z = MFMA(aH1, BHH[1][1], Z, 0,0,0);
        Z = MFMA(aL1, BHH[1][1], Z, 0,0,0);
        Z = MFMA(xf,  BIH[1],    Z, 0,0,0);
        f32x4 Hh = MFMA(aH0, BHH[2][0], bH4, 0,0,0);
        Hh = MFMA(aL0, BHH[2][0], Hh, 0,0,0);
        Hh = MFMA(aH1, BHH[2][1], Hh, 0,0,0);
        Hh = MFMA(aL1, BHH[2][1], Hh, 0,0,0);
        f32x4 I = MFMA(xf, BIH[2], bI4, 0,0,0);

        char* hw = (char*)&sHhi[p^1][0];
        char* lw = (char*)&sHlo[p^1][0];
#pragma unroll
        for (int q = 0; q < 4; ++q) {
            float rr = sigm(R[q]);
            float zz = sigm(Z[q]);
            float nn = tanhf_(fmaf(rr, Hh[q], I[q]));
            float hq = nn + zz*(h[q] - nn);
            h[q] = hq;
            unsigned hb2 = fbits(hq) & 0xffff0000u;
            *(unsigned short*)(hw + pubOff[q]) = (unsigned short)(hb2 >> 16);
            *(unsigned short*)(lw + pubOff[q]) = (unsigned short)(fbits(hq - bitsf(hb2)) >> 16);
        }
    };

    auto readXE2 = [&](unsigned bo, int sb) -> short8 {
        u32x4 A = *(const u32x4*)(sXB + (bo + rdEA + (unsigned)sb));
        u32x4 B = *(const u32x4*)(sXB + (bo + rdEB + (unsigned)sb));
        i32x4 f;
        f[0] = (int)__builtin_amdgcn_perm(A[1], A[0], s01E);
        f[1] = (int)__builtin_amdgcn_perm(A[3], A[2], s01E);
        f[2] = (int)__builtin_amdgcn_perm(B[1], B[0], s23E);
        f[3] = (int)__builtin_amdgcn_perm(B[3], B[2], s23E);
        return s8(f);
    };
    auto readXD2 = [&](unsigned bo, int sb, unsigned pw, bool dopatch) -> short8 {
        u32x4 A = *(const u32x4*)(sXB + (bo + rdDA + (unsigned)sb));
        u32x4 B = *(const u32x4*)(sXB + (bo + rdDB + (unsigned)sb));
        if (dopatch) {             // pred into feature 4 (hi+lo via packed word)
            if (pA_) A[0] = pw;
            if (pB_) B[0] = pw;
        }
        i32x4 f;
        f[0] = (int)__builtin_amdgcn_perm(A[1], A[0], s01D);
        f[1] = (int)__builtin_amdgcn_perm(A[3], A[2], s01D);
        f[2] = (int)__builtin_amdgcn_perm(B[1], B[0], s23D);
        f[3] = (int)__builtin_amdgcn_perm(B[3], B[2], s23D);
        return s8(f);
    };

    // ---------------- prologue ----------------
    {   // h0 = 0 into parity-0 buffers
        unsigned* z0 = (unsigned*)&sHhi[0][0];
        unsigned* z1 = (unsigned*)&sHlo[0][0];
#pragma unroll
        for (int it = 0; it < 2; ++it) { z0[tid + 256*it] = 0u; z1[tid + 256*it] = 0u; }
    }
    // zero slot words 11..15 (encoder f11 pad + permanent zero block), both buffers
#pragma unroll
    for (int it = 0; it < 5; ++it) {
        int e = tid + 256*it;
        int b = e / 640, r = (e - b*640) / 40, rem = e % 40;
        int slot = rem / 5, wd = 11 + rem % 5;
        sX[b*(16*XROW) + r*XROW + slot*16 + wd] = 0u;
    }
    loadPhase(eWih, eWhh, eBih, eBhh, N_FEAT);
    {   // stage encoder chunk 0 (pre-packed)
        float sv[6];
#pragma unroll
        for (int n = 0; n < 5; ++n) sv[n] = gP[16*n];
        sv[5] = (sli < 8) ? gP[80] : 0.0f;
#pragma unroll
        for (int n = 0; n < 5; ++n) *(unsigned*)(sXwr + offE[n]) = packw(sv[n]);
        if (sli < 8) *(unsigned*)(sXwr + offE[5]) = packw(sv[5]);
    }

    // ---------------- encoder: 21 chunks x 8 steps ----------------
    for (int ch = 0; ch < 21; ++ch) {
        const unsigned bo  = (unsigned)((ch & 1) * BUFB);
        const unsigned wbo = (unsigned)(((ch + 1) & 1) * BUFB);
        const bool st = (ch < 20);
        float sv[6];
#pragma unroll
        for (int s = 0; s < 8; ++s) {
            __syncthreads();
            if (s == 0 && st) {              // issue next-chunk loads (full-chunk latency cover)
                const float* sp = gP + 88*(ch+1);
#pragma unroll
                for (int n = 0; n < 5; ++n) sv[n] = sp[16*n];
                sv[5] = (sli < 8) ? sp[80] : 0.0f;
            }
            short8 xf = readXE2(bo, s*64);
            gru_step(s & 1, xf);
            if (s == 0 && st) {              // write to the other buffer (disjoint, no extra barrier)
#pragma unroll
                for (int n = 0; n < 5; ++n) *(unsigned*)(sXwr + wbo + offE[n]) = packw(sv[n]);
                if (sli < 8) *(unsigned*)(sXwr + wbo + offE[5]) = packw(sv[5]);
            }
        }
    }

    // ---------------- decoder setup ----------------
    __syncthreads();   // all encoder sX reads done before pad rewrites
    loadPhase(dWih, dWhh, dBih, dBhh, DEC_FEAT);
    const float fwc = fcW[u*16 + c];
    const float fb  = fcB[0];
#pragma unroll
    for (int it = 0; it < 4; ++it) {         // zero decoder pad words 7..10, both buffers
        int e = tid + 256*it;
        int b = e / 512, r = (e - b*512) / 32, rem = e % 32;
        int slot = rem / 4, wd = 7 + (rem & 3);
        sX[b*(16*XROW) + r*XROW + slot*16 + wd] = 0u;
    }
    {   // stage decoder chunk 0
        float sv[4];
#pragma unroll
        for (int n = 0; n < 3; ++n) sv[n] = gT[16*n];
        sv[3] = (sli < 8) ? gT[48] : 0.0f;
#pragma unroll
        for (int n = 0; n < 3; ++n) *(unsigned*)(sXwr + offD[n]) = packw(sv[n]);
        if (sli < 8) *(unsigned*)(sXwr + offD[3]) = packw(sv[3]);
    }

    // ---------------- decoder: 6 chunks x 8 steps ----------------
    for (int ch = 0; ch < 6; ++ch) {
        const unsigned bo  = (unsigned)((ch & 1) * BUFB);
        const unsigned wbo = (unsigned)(((ch + 1) & 1) * BUFB);
        const bool st = (ch < 5);
        float sv[4];
#pragma unroll
        for (int s = 0; s < 8; ++s) {
            const int i = ch*8 + s;
            __syncthreads();
            if (s == 0 && st) {
                const float* sp = gT + 56*(ch+1);
#pragma unroll
                for (int n = 0; n < 3; ++n) sv[n] = sp[16*n];
                sv[3] = (sli < 8) ? sp[48] : 0.0f;
            }
            unsigned pw = 0u;
            const bool hasPred = (s > 0) || (ch > 0);
            if (hasPred) {                    // pred_{i-1} from parity (s&1)^1 partials
                f32x4 pp = *(const f32x4*)&sPartial[(s & 1) ^ 1][c][0];
                float pred = pp[0] + pp[1] + pp[2] + pp[3] + fb;
                pw = packw(pred);
                if (u == 0 && g == 0)
                    out[(size_t)(row0 + c)*T_DEC + (i - 1)] = pred;
            }
            short8 xf = readXD2(bo, s*64, pw, hasPred);
            gru_step(s & 1, xf);
            // fc partials over this wave's 16 units
#pragma unroll
            for (int q = 0; q < 4; ++q) {
                float v = h[q] * fwc;
                v += __shfl_xor(v, 1, 64);
                v += __shfl_xor(v, 2, 64);
                v += __shfl_xor(v, 4, 64);
                v += __shfl_xor(v, 8, 64);
                if (c == 0) sPartial[s & 1][g*4 + q][u] = v;
            }
            if (s == 0 && st) {
#pragma unroll
                for (int n = 0; n < 3; ++n) *(unsigned*)(sXwr + wbo + offD[n]) = packw(sv[n]);
                if (sli < 8) *(unsigned*)(sXwr + wbo + offD[3]) = packw(sv[3]);
            }
        }
    }
    __syncthreads();
    if (u == 0 && g == 0) {   // final pred (i = 47, parity 1)
        f32x4 pp = *(const f32x4*)&sPartial[1][c][0];
        float pred = pp[0] + pp[1] + pp[2] + pp[3] + fb;
        out[(size_t)(row0 + c)*T_DEC + (T_DEC - 1)] = pred;
    }
}

extern "C" void kernel_launch(void* const* d_in, const int* in_sizes, int n_in,
                              void* d_out, int out_size, void* d_ws, size_t ws_size,
                              hipStream_t stream)
{
    const float* prior   = (const float*)d_in[0];
    const float* teacher = (const float*)d_in[1];
    const float* eWih    = (const float*)d_in[2];
    const float* eWhh    = (const float*)d_in[3];
    const float* eBih    = (const float*)d_in[4];
    const float* eBhh    = (const float*)d_in[5];
    const float* dWih    = (const float*)d_in[6];
    const float* dWhh    = (const float*)d_in[7];
    const float* dBih    = (const float*)d_in[8];
    const float* dBhh    = (const float*)d_in[9];
    const float* fcW     = (const float*)d_in[10];
    const float* fcB     = (const float*)d_in[11];
    float* out = (float*)d_out;

    dim3 grid(BATCH / 16);    // 512 blocks x 4 waves; LDS sized for 4 blocks/CU co-residency
    dim3 block(256);
    hipLaunchKernelGGL(gru_mfma, grid, block, 0, stream,
                       prior, teacher, eWih, eWhh, eBih, eBhh,
                       dWih, dWhh, dBih, dBhh, fcW, fcB, out);
}